// Round 7
// baseline (426.894 us; speedup 1.0000x reference)
//
#include <hip/hip_runtime.h>
#include <cstdint>
#include <cstddef>

// GAT layer, N=8192, Fin=128, Fout=64.
// h = elu( softmax_j(mask(leaky_relu(Wh1_i + Wh2_j))) @ Wh )
// R11: adj -> 8 MB bitmask prepass (gat_mask, pure streaming read of the
// 268 MB adj). phaseB loads its task's entire adj slice as bits in the
// prologue (8 VGPR) -> the HBM latency chain is GONE from the body; only the
// distance-1 L2 group (w2+B) remains. Freed registers -> 4 waves/SIMD.
// Rationale: R9 (-34us, fewer wait-points/work) vs R10 (null, same wait
// points served from L1) => phaseB is latency-chain-bound. Select-vs-mul
// keeps the math bit-identical to R10.

#define NN   8192
#define FIN  128
#define FOUT 64
#define SJ   16                // j-split per 32-row group: 256*SJ = 4096 tasks
#define JCHUNK (NN / SJ)       // 512 columns per wave -> 16 blocks of 32

typedef __attribute__((ext_vector_type(8))) short   short8;   // 8 bf16 (4 VGPRs)
typedef __attribute__((ext_vector_type(4))) float   f32x4;
typedef __attribute__((ext_vector_type(4))) unsigned int u32x4;

#define LOG2E 1.44269504088896340736f

// ---------------------------------------------------------------- mask -----
// adj (0.0/1.0 f32) -> bitmask, pre-swizzled for phaseB's lane layout:
// maskb[row*1024 + jc*64 + q*16 + b] = bits of adj[row][jc*512 + b*32 + q*8
// .. +7] (bit e = col q*8+e). Lane L covers block b=L>>2, quad q=L&3.
// Pure streaming: 268 MB read, 8 MB write, no dependencies.
__global__ __launch_bounds__(256) void gat_mask(
    const float* __restrict__ adj, unsigned char* __restrict__ maskb)
{
  const int wid  = threadIdx.x >> 6;
  const int lane = threadIdx.x & 63;
  const int row  = blockIdx.x;
  const float* ar = adj + (size_t)row * NN;
  unsigned char* mr = maskb + (size_t)row * (NN / 8);
#pragma unroll
  for (int k = 0; k < 4; ++k) {
    const int c = wid + 4 * k;                 // chunk 0..15
    const float* p = ar + c * 512 + lane * 8;
    f32x4 v0 = *(const f32x4*)(p);
    f32x4 v1 = *(const f32x4*)(p + 4);
    unsigned int byte = 0;
#pragma unroll
    for (int e = 0; e < 4; ++e) {
      byte |= (v0[e] > 0.f) ? (1u << e)       : 0u;
      byte |= (v1[e] > 0.f) ? (1u << (4 + e)) : 0u;
    }
    mr[c * 64 + (lane & 3) * 16 + (lane >> 2)] = (unsigned char)byte;
  }
}

// ---------------------------------------------------------------- Phase A ---
// One wave per 4 rows: Wh[row][f] (f = lane), store bf16 transposed
// Whbt[f][row], wave-reduce Wh1 = Wh.a1, Wh2 = Wh.a2 (pre-scaled by log2e so
// phaseB uses exp2 directly; leaky_relu commutes with positive scaling).
__global__ __launch_bounds__(256) void gat_phaseA(
    const float* __restrict__ x, const float* __restrict__ W,
    const float* __restrict__ a, unsigned short* __restrict__ Whbt,
    float* __restrict__ Wh1, float* __restrict__ Wh2)
{
  const int wid  = threadIdx.x >> 6;
  const int lane = threadIdx.x & 63;
  const int row0 = (blockIdx.x * 4 + wid) * 4;
  const float a1 = a[lane];
  const float a2 = a[FOUT + lane];
  float acc[4] = {0.f, 0.f, 0.f, 0.f};
#pragma unroll 4
  for (int k = 0; k < FIN; k += 4) {
    float4 wv0 = make_float4(W[(k+0)*FOUT + lane], W[(k+1)*FOUT + lane],
                             W[(k+2)*FOUT + lane], W[(k+3)*FOUT + lane]);
#pragma unroll
    for (int r = 0; r < 4; ++r) {
      float4 xv = *(const float4*)(x + (row0 + r) * FIN + k);
      acc[r] = fmaf(xv.x, wv0.x, acc[r]);
      acc[r] = fmaf(xv.y, wv0.y, acc[r]);
      acc[r] = fmaf(xv.z, wv0.z, acc[r]);
      acc[r] = fmaf(xv.w, wv0.w, acc[r]);
    }
  }
#pragma unroll
  for (int r = 0; r < 4; ++r) {
    // bf16 round-to-nearest-even
    unsigned int u = __float_as_uint(acc[r]);
    unsigned int rb = (u + 0x7FFFu + ((u >> 16) & 1u)) >> 16;
    Whbt[lane * NN + row0 + r] = (unsigned short)rb;
    float s1 = acc[r] * a1, s2 = acc[r] * a2;
#pragma unroll
    for (int off = 32; off; off >>= 1) {
      s1 += __shfl_xor(s1, off);
      s2 += __shfl_xor(s2, off);
    }
    if (lane == 0) { Wh1[row0 + r] = s1 * LOG2E; Wh2[row0 + r] = s2 * LOG2E; }
  }
}

// ---------------------------------------------------------------- Phase B ---
// Wave task = (rowGroup of 32 rows) x (j-chunk of 512). Two 16-row sub-tiles
// share every B-frag and Wh2 load; 4 waves/WG share the j-chunk (same-XCD L2
// for B/mask). Whole-task adj bits live in 2 dwordx4 (mk0/mk1) from the
// prologue -> body's only memory dependency is the distance-1 L2 group.
// 16 blocks of 32 cols, unrolled x2 ping-pong.
#define AF_ONE(AF, BYTE, W20, W21, WH1, RS)                              \
    _Pragma("unroll")                                                    \
    for (int e = 0; e < 4; ++e) {                                        \
      float t0 = (WH1) + (W20)[e];                                       \
      t0 = fmaxf(t0, 0.2f * t0);            /* leaky_relu, scale-inv */  \
      float p0 = ((BYTE) & (1u << e)) ? exp2f(t0) : 0.0f;                \
      unsigned int pu0 = __float_as_uint(p0) & 0xFFFF0000u;              \
      RS += __uint_as_float(pu0);           /* denom matches bf16 num */ \
      AF[e] = (short)(pu0 >> 16);                                        \
      float t1 = (WH1) + (W21)[e];                                       \
      t1 = fmaxf(t1, 0.2f * t1);                                         \
      float p1 = ((BYTE) & (1u << (4 + e))) ? exp2f(t1) : 0.0f;          \
      unsigned int pu1 = __float_as_uint(p1) & 0xFFFF0000u;              \
      RS += __uint_as_float(pu1);                                        \
      AF[4 + e] = (short)(pu1 >> 16);                                    \
    }

#define GAT_BODY(T, W2C0, W2C1, BC0, BC1, BC2, BC3,                      \
                 W2N0, W2N1, BN0, BN1, BN2, BN3, JN1)                    \
  {                                                                      \
    W2N0 = *(const f32x4*)(w2base + (JN1));                              \
    W2N1 = *(const f32x4*)(w2base + (JN1) + 4);                          \
    BN0  = *(const short8*)(bbase + (JN1));                              \
    BN1  = *(const short8*)(bbase + (JN1) + 16 * NN);                    \
    BN2  = *(const short8*)(bbase + (JN1) + 32 * NN);                    \
    BN3  = *(const short8*)(bbase + (JN1) + 48 * NN);                    \
    const unsigned int by0 = (mk0[(T) >> 2] >> (((T) & 3) * 8)) & 0xffu; \
    const unsigned int by1 = (mk1[(T) >> 2] >> (((T) & 3) * 8)) & 0xffu; \
    short8 af0, af1;                                                     \
    AF_ONE(af0, by0, W2C0, W2C1, wh1_0, rsum0);                          \
    AF_ONE(af1, by1, W2C0, W2C1, wh1_1, rsum1);                          \
    c00 = __builtin_amdgcn_mfma_f32_16x16x32_bf16(af0, BC0, c00, 0,0,0); \
    c01 = __builtin_amdgcn_mfma_f32_16x16x32_bf16(af0, BC1, c01, 0,0,0); \
    c02 = __builtin_amdgcn_mfma_f32_16x16x32_bf16(af0, BC2, c02, 0,0,0); \
    c03 = __builtin_amdgcn_mfma_f32_16x16x32_bf16(af0, BC3, c03, 0,0,0); \
    c10 = __builtin_amdgcn_mfma_f32_16x16x32_bf16(af1, BC0, c10, 0,0,0); \
    c11 = __builtin_amdgcn_mfma_f32_16x16x32_bf16(af1, BC1, c11, 0,0,0); \
    c12 = __builtin_amdgcn_mfma_f32_16x16x32_bf16(af1, BC2, c12, 0,0,0); \
    c13 = __builtin_amdgcn_mfma_f32_16x16x32_bf16(af1, BC3, c13, 0,0,0); \
  }

__global__ __launch_bounds__(256, 4) void gat_phaseB(
    const unsigned char* __restrict__ maskb, const unsigned short* __restrict__ Whbt,
    const float* __restrict__ Wh1, const float* __restrict__ Wh2,
    float* __restrict__ accbuf, float* __restrict__ denbuf, int nslices)
{
  const int wid  = threadIdx.x >> 6;
  const int lane = threadIdx.x & 63;
  // 4 waves of a WG share the j-chunk, cover 4 row-groups
  const int jc   = blockIdx.x % SJ;
  const int rg   = (blockIdx.x / SJ) * 4 + wid;   // 32-row group
  const int m = lane & 15;
  const int q = lane >> 4;
  const int r0 = rg * 32 + m;
  const int r1 = r0 + 16;
  const float wh1_0 = Wh1[r0];
  const float wh1_1 = Wh1[r1];
  const unsigned short* bbase = Whbt + m * NN + q * 8;   // feat row ft*16+m
  const float* w2base = Wh2 + q * 8;

  // whole-task adj bits: 16 bytes per row (16 blocks x 8 cols of quad q)
  const u32x4 mk0 = *(const u32x4*)(maskb + (size_t)r0 * (NN/8) + jc * 64 + q * 16);
  const u32x4 mk1 = *(const u32x4*)(maskb + (size_t)r1 * (NN/8) + jc * 64 + q * 16);

  f32x4 c00 = {0.f,0.f,0.f,0.f}, c01 = c00, c02 = c00, c03 = c00;
  f32x4 c10 = c00, c11 = c00, c12 = c00, c13 = c00;
  float rsum0 = 0.f, rsum1 = 0.f;

  const int jbeg = jc * JCHUNK;

  // ping-pong slots: A = even blocks, B = odd blocks
  f32x4 w2A0, w2A1, w2B0, w2B1;
  short8 bA0, bA1, bA2, bA3, bB0, bB1, bB2, bB3;

  // prologue: L2 data for block 0
  w2A0 = *(const f32x4*)(w2base + jbeg);
  w2A1 = *(const f32x4*)(w2base + jbeg + 4);
  bA0  = *(const short8*)(bbase + jbeg);
  bA1  = *(const short8*)(bbase + jbeg + 16 * NN);
  bA2  = *(const short8*)(bbase + jbeg + 32 * NN);
  bA3  = *(const short8*)(bbase + jbeg + 48 * NN);

  // 16 blocks of 32 columns; unrolled x2 -> 8 static double-bodies. Tail
  // "next" loads wrap to jbeg (valid addresses, values unused).
#pragma unroll
  for (int bb = 0; bb < 16; bb += 2) {
    const int j1 = (bb + 1 < 16) ? (bb + 1) * 32 : 0;
    const int j2 = (bb + 2 < 16) ? (bb + 2) * 32 : 0;
    GAT_BODY(bb,     w2A0, w2A1, bA0, bA1, bA2, bA3,
             w2B0, w2B1, bB0, bB1, bB2, bB3, jbeg + j1);
    GAT_BODY(bb + 1, w2B0, w2B1, bB0, bB1, bB2, bB3,
             w2A0, w2A1, bA0, bA1, bA2, bA3, jbeg + j2);
  }

  // row-sums: combine the 4 k-quads; every lane ends with full sum for its m
  rsum0 += __shfl_xor(rsum0, 16);
  rsum0 += __shfl_xor(rsum0, 32);
  rsum1 += __shfl_xor(rsum1, 16);
  rsum1 += __shfl_xor(rsum1, 32);

  const int slice = (nslices > 1) ? jc : 0;
  float* accout = accbuf + (size_t)slice * (NN * FOUT);
  float* denout = denbuf + slice * NN;
  f32x4 cc0[4] = {c00, c01, c02, c03};
  f32x4 cc1[4] = {c10, c11, c12, c13};
  if (nslices > 1) {            // roomy ws: plain per-slice stores
    if (q == 0) { denout[r0] = rsum0; denout[r1] = rsum1; }
#pragma unroll
    for (int ft = 0; ft < 4; ++ft)
#pragma unroll
      for (int r = 0; r < 4; ++r) {
        accout[(rg * 32 +      q * 4 + r) * FOUT + ft * 16 + m] = cc0[ft][r];
        accout[(rg * 32 + 16 + q * 4 + r) * FOUT + ft * 16 + m] = cc1[ft][r];
      }
  } else {                      // tight ws: atomic accumulate (zeroed first)
    if (q == 0) { atomicAdd(&denout[r0], rsum0); atomicAdd(&denout[r1], rsum1); }
#pragma unroll
    for (int ft = 0; ft < 4; ++ft)
#pragma unroll
      for (int r = 0; r < 4; ++r) {
        atomicAdd(&accout[(rg * 32 +      q * 4 + r) * FOUT + ft * 16 + m], cc0[ft][r]);
        atomicAdd(&accout[(rg * 32 + 16 + q * 4 + r) * FOUT + ft * 16 + m], cc1[ft][r]);
      }
  }
}

// ---------------------------------------------------------------- Phase C ---
// elu(acc/den), vectorized f32x4 per thread.
__global__ __launch_bounds__(256) void gat_phaseC(
    const float* __restrict__ accbuf, const float* __restrict__ denbuf,
    float* __restrict__ out, int nslices)
{
  const int idx4 = blockIdx.x * 256 + threadIdx.x;   // f32x4 index
  const int idx  = idx4 * 4;
  const int row  = idx >> 6;    // FOUT = 64; 4 elems stay within one row
  f32x4 s = {0.f, 0.f, 0.f, 0.f};
  float d = 0.f;
  for (int sl = 0; sl < nslices; ++sl) {
    f32x4 v = *(const f32x4*)(accbuf + (size_t)sl * (NN * FOUT) + idx);
    s += v;
    d += denbuf[sl * NN + row];
  }
  float inv = 1.0f / d;
  f32x4 o;
#pragma unroll
  for (int e = 0; e < 4; ++e) {
    float v = s[e] * inv;
    o[e] = (v > 0.f) ? v : expm1f(v);   // elu, alpha=1
  }
  *(f32x4*)(out + idx) = o;
}

// ------------------------------------------------------------------ launch --
extern "C" void kernel_launch(void* const* d_in, const int* in_sizes, int n_in,
                              void* d_out, int out_size, void* d_ws, size_t ws_size,
                              hipStream_t stream)
{
  const float* x   = (const float*)d_in[0];   // [8192,128]
  const float* adj = (const float*)d_in[1];   // [8192,8192]
  const float* W   = (const float*)d_in[2];   // [128,64]
  const float* a   = (const float*)d_in[3];   // [128,1]
  float* out = (float*)d_out;                 // [8192,64] fp32

  const size_t accEl = (size_t)NN * FOUT;
  const size_t maskBytes = (size_t)NN * (NN / 8);   // 8 MB
  const size_t roomyBytes = (size_t)SJ * accEl * 4 + (size_t)SJ * NN * 4
                          + (size_t)NN * 8 + (size_t)FOUT * NN * 2 + maskBytes;
  const int nslices = (ws_size >= roomyBytes) ? SJ : 1;

  char* ws = (char*)d_ws;
  float* accbuf = (float*)ws;
  size_t off = (size_t)nslices * accEl * 4;
  float* denbuf = (float*)(ws + off); off += (size_t)nslices * NN * 4;
  float* Wh1 = (float*)(ws + off);    off += (size_t)NN * 4;
  float* Wh2 = (float*)(ws + off);    off += (size_t)NN * 4;
  unsigned short* Whbt = (unsigned short*)(ws + off); off += (size_t)FOUT * NN * 2;
  unsigned char* maskb = (unsigned char*)(ws + off);

  if (nslices == 1)   // atomic path needs zeroed acc+den (contiguous)
    hipMemsetAsync(accbuf, 0, accEl * 4 + (size_t)NN * 4, stream);

  gat_mask<<<NN, 256, 0, stream>>>(adj, maskb);
  gat_phaseA<<<NN / 16, 256, 0, stream>>>(x, W, a, Whbt, Wh1, Wh2);
  gat_phaseB<<<((NN / 32) * SJ) / 4, 256, 0, stream>>>(maskb, Whbt, Wh1, Wh2,
                                                       accbuf, denbuf, nslices);
  gat_phaseC<<<(NN * FOUT) / 4 / 256, 256, 0, stream>>>(accbuf, denbuf, out, nslices);
}

// Round 8
// 394.490 us; speedup vs baseline: 1.0821x; 1.0821x over previous
//
#include <hip/hip_runtime.h>
#include <cstdint>
#include <cstddef>

// GAT layer, N=8192, Fin=128, Fout=64.
// h = elu( softmax_j(mask(leaky_relu(Wh1_i + Wh2_j))) @ Wh )
// R12 = R10 (393us champion: 32 rows/wave, jc-shared WG mapping, distance-2
// NT adj stream) + pre-packed B operand. R11 taught: phaseB's ~90us floor is
// body-internal (adj-independent); the B-gather was 16 half-used 128B lines
// per load (64 line-reqs/body/wave). phaseA now emits WhP[block][ft][lane] =
// exactly lane (m,q)'s 16B MFMA fragment -> phaseB B-loads are dense
// lane-linear dwordx4 (8 full lines/instr, 2x fewer line-reqs, L1-shared
// across the WG's 4 same-jc waves). sched_barrier pins protect the prefetch
// pipeline from sinking. Mask prepass deleted (serial 50us never pays).

#define NN   8192
#define FIN  128
#define FOUT 64
#define SJ   16                // j-split per 32-row group: 256*SJ = 4096 tasks
#define JCHUNK (NN / SJ)       // 512 columns per wave -> 16 blocks of 32

typedef __attribute__((ext_vector_type(8))) short   short8;   // 8 bf16 (4 VGPRs)
typedef __attribute__((ext_vector_type(4))) float   f32x4;

#define LOG2E 1.44269504088896340736f
#define NTL(p) __builtin_nontemporal_load((const f32x4*)(p))

// ---------------------------------------------------------------- Phase A ---
// One wave per 4 rows: Wh[row][f] (f = lane). Emits:
//  - WhP packed B-fragments: WhP[(B0*4+ft)*512 + lane*8 + e] =
//      bf16(Wh[B0*32 + (lane>>4)*8 + e][ (ft*16) + (lane&15) ])
//    i.e. exactly the 16B lane (m,q) consumes as MFMA-B in phaseB.
//  - Wh1/Wh2 = Wh.a1 / Wh.a2, pre-scaled by log2e (exp2 domain; leaky_relu
//    commutes with positive scaling).
__global__ __launch_bounds__(256) void gat_phaseA(
    const float* __restrict__ x, const float* __restrict__ W,
    const float* __restrict__ a, unsigned short* __restrict__ WhP,
    float* __restrict__ Wh1, float* __restrict__ Wh2)
{
  const int wid  = threadIdx.x >> 6;
  const int lane = threadIdx.x & 63;
  const int row0 = (blockIdx.x * 4 + wid) * 4;
  const float a1 = a[lane];
  const float a2 = a[FOUT + lane];
  float acc[4] = {0.f, 0.f, 0.f, 0.f};
#pragma unroll 4
  for (int k = 0; k < FIN; k += 4) {
    float4 wv0 = make_float4(W[(k+0)*FOUT + lane], W[(k+1)*FOUT + lane],
                             W[(k+2)*FOUT + lane], W[(k+3)*FOUT + lane]);
#pragma unroll
    for (int r = 0; r < 4; ++r) {
      float4 xv = *(const float4*)(x + (row0 + r) * FIN + k);
      acc[r] = fmaf(xv.x, wv0.x, acc[r]);
      acc[r] = fmaf(xv.y, wv0.y, acc[r]);
      acc[r] = fmaf(xv.z, wv0.z, acc[r]);
      acc[r] = fmaf(xv.w, wv0.w, acc[r]);
    }
  }
  const int ft = lane >> 4, m = lane & 15;
#pragma unroll
  for (int r = 0; r < 4; ++r) {
    const int row = row0 + r;
    // bf16 round-to-nearest-even
    unsigned int u = __float_as_uint(acc[r]);
    unsigned int rb = (u + 0x7FFFu + ((u >> 16) & 1u)) >> 16;
    // packed-fragment dest: B0=row>>5, q=(row>>3)&3, e=row&7
    const int B0 = row >> 5, qq = (row >> 3) & 3, e = row & 7;
    WhP[(size_t)(B0 * 4 + ft) * 512 + (qq * 16 + m) * 8 + e] = (unsigned short)rb;
    float s1 = acc[r] * a1, s2 = acc[r] * a2;
#pragma unroll
    for (int off = 32; off; off >>= 1) {
      s1 += __shfl_xor(s1, off);
      s2 += __shfl_xor(s2, off);
    }
    if (lane == 0) { Wh1[row] = s1 * LOG2E; Wh2[row] = s2 * LOG2E; }
  }
}

// ---------------------------------------------------------------- Phase B ---
// Wave task = (rowGroup of 32 rows) x (j-chunk of 512). Two 16-row sub-tiles
// share every B-frag and Wh2 load; 4 waves/WG share the j-chunk (identical
// WhP/Wh2 addresses -> L1 serves 3 of 4). A-frags (P) in registers: lane
// holds rows m=lane&15 (+0/+16), k=(lane>>4)*8+e. 16 blocks of 32 cols,
// unrolled x2 static ping-pong: adj distance 2 (NT), Wh2/B distance 1.
// Issue order per body: [next-block w2+B dense loads] -> pin -> af compute ->
// [adj prefetch block+2] -> pin -> 8 MFMA.
#define AF_ONE(AF, AD0, AD1, W20, W21, WH1, RS)                          \
    _Pragma("unroll")                                                    \
    for (int e = 0; e < 4; ++e) {                                        \
      float t0 = (WH1) + (W20)[e];                                       \
      t0 = fmaxf(t0, 0.2f * t0);            /* leaky_relu, scale-inv */  \
      float p0 = exp2f(t0) * (AD0)[e];      /* mask: adj is 0.0/1.0 */   \
      unsigned int pu0 = __float_as_uint(p0) & 0xFFFF0000u;              \
      RS += __uint_as_float(pu0);           /* denom matches bf16 num */ \
      AF[e] = (short)(pu0 >> 16);                                        \
      float t1 = (WH1) + (W21)[e];                                       \
      t1 = fmaxf(t1, 0.2f * t1);                                         \
      float p1 = exp2f(t1) * (AD1)[e];                                   \
      unsigned int pu1 = __float_as_uint(p1) & 0xFFFF0000u;              \
      RS += __uint_as_float(pu1);                                        \
      AF[4 + e] = (short)(pu1 >> 16);                                    \
    }

#define GAT_BODY(AD00, AD01, AD10, AD11, W2C0, W2C1, BC0, BC1, BC2, BC3, \
                 W2N0, W2N1, BN0, BN1, BN2, BN3, JN1, BLK1, JN2)         \
  {                                                                      \
    W2N0 = *(const f32x4*)(w2base + (JN1));                              \
    W2N1 = *(const f32x4*)(w2base + (JN1) + 4);                          \
    BN0  = *(const short8*)(wpbase + (size_t)(BLK1) * 2048);             \
    BN1  = *(const short8*)(wpbase + (size_t)(BLK1) * 2048 + 512);       \
    BN2  = *(const short8*)(wpbase + (size_t)(BLK1) * 2048 + 1024);      \
    BN3  = *(const short8*)(wpbase + (size_t)(BLK1) * 2048 + 1536);      \
    __builtin_amdgcn_sched_barrier(0);                                   \
    short8 af0, af1;                                                     \
    AF_ONE(af0, AD00, AD01, W2C0, W2C1, wh1_0, rsum0);                   \
    AF_ONE(af1, AD10, AD11, W2C0, W2C1, wh1_1, rsum1);                   \
    AD00 = NTL(adjrow0 + (JN2)); AD01 = NTL(adjrow0 + (JN2) + 4);        \
    AD10 = NTL(adjrow1 + (JN2)); AD11 = NTL(adjrow1 + (JN2) + 4);        \
    __builtin_amdgcn_sched_barrier(0);                                   \
    c00 = __builtin_amdgcn_mfma_f32_16x16x32_bf16(af0, BC0, c00, 0,0,0); \
    c01 = __builtin_amdgcn_mfma_f32_16x16x32_bf16(af0, BC1, c01, 0,0,0); \
    c02 = __builtin_amdgcn_mfma_f32_16x16x32_bf16(af0, BC2, c02, 0,0,0); \
    c03 = __builtin_amdgcn_mfma_f32_16x16x32_bf16(af0, BC3, c03, 0,0,0); \
    c10 = __builtin_amdgcn_mfma_f32_16x16x32_bf16(af1, BC0, c10, 0,0,0); \
    c11 = __builtin_amdgcn_mfma_f32_16x16x32_bf16(af1, BC1, c11, 0,0,0); \
    c12 = __builtin_amdgcn_mfma_f32_16x16x32_bf16(af1, BC2, c12, 0,0,0); \
    c13 = __builtin_amdgcn_mfma_f32_16x16x32_bf16(af1, BC3, c13, 0,0,0); \
  }

__global__ __launch_bounds__(256, 3) void gat_phaseB(
    const float* __restrict__ adj, const unsigned short* __restrict__ WhP,
    const float* __restrict__ Wh1, const float* __restrict__ Wh2,
    float* __restrict__ accbuf, float* __restrict__ denbuf, int nslices)
{
  const int wid  = threadIdx.x >> 6;
  const int lane = threadIdx.x & 63;
  // 4 waves of a WG share the j-chunk, cover 4 row-groups
  const int jc   = blockIdx.x % SJ;
  const int rg   = (blockIdx.x / SJ) * 4 + wid;   // 32-row group
  const int m = lane & 15;
  const int q = lane >> 4;
  const int r0 = rg * 32 + m;
  const int r1 = r0 + 16;
  const float wh1_0 = Wh1[r0];
  const float wh1_1 = Wh1[r1];
  // per-lane bases with the q*8 element offset folded in
  const float* adjrow0 = adj + (size_t)r0 * NN + q * 8;
  const float* adjrow1 = adj + (size_t)r1 * NN + q * 8;
  // packed-B base: lane's 16B fragment; block b of this jc at +b*2048 shorts
  const unsigned short* wpbase = WhP + (size_t)(jc * 16) * 2048 + lane * 8;
  const float* w2base = Wh2 + q * 8;

  f32x4 c00 = {0.f,0.f,0.f,0.f}, c01 = c00, c02 = c00, c03 = c00;
  f32x4 c10 = c00, c11 = c00, c12 = c00, c13 = c00;
  float rsum0 = 0.f, rsum1 = 0.f;

  const int jbeg = jc * JCHUNK;

  // ping-pong slots: A = even blocks, B = odd blocks
  f32x4 w2A0, w2A1, w2B0, w2B1;
  short8 bA0, bA1, bA2, bA3, bB0, bB1, bB2, bB3;
  f32x4 adA00, adA01, adA10, adA11;    // sub-tile 0/1, block-even
  f32x4 adB00, adB01, adB10, adB11;    // block-odd

  // prologue: L2 data for block 0, adj for blocks 0 and 1
  w2A0 = *(const f32x4*)(w2base + jbeg);
  w2A1 = *(const f32x4*)(w2base + jbeg + 4);
  bA0  = *(const short8*)(wpbase);
  bA1  = *(const short8*)(wpbase + 512);
  bA2  = *(const short8*)(wpbase + 1024);
  bA3  = *(const short8*)(wpbase + 1536);
  adA00 = NTL(adjrow0 + jbeg);      adA01 = NTL(adjrow0 + jbeg + 4);
  adA10 = NTL(adjrow1 + jbeg);      adA11 = NTL(adjrow1 + jbeg + 4);
  adB00 = NTL(adjrow0 + jbeg + 32); adB01 = NTL(adjrow0 + jbeg + 36);
  adB10 = NTL(adjrow1 + jbeg + 32); adB11 = NTL(adjrow1 + jbeg + 36);

  // 16 blocks of 32 columns; unrolled x2 -> 8 static double-bodies. Tail
  // "next" loads wrap to block 0 (valid addresses, values unused).
#pragma unroll
  for (int bb = 0; bb < 16; bb += 2) {
    const int b1 = (bb + 1 < 16) ? bb + 1 : 0;
    const int b2 = (bb + 2 < 16) ? bb + 2 : 0;
    const int b3 = (bb + 3 < 16) ? bb + 3 : 0;
    GAT_BODY(adA00, adA01, adA10, adA11, w2A0, w2A1, bA0, bA1, bA2, bA3,
             w2B0, w2B1, bB0, bB1, bB2, bB3, jbeg + b1 * 32, b1, jbeg + b2 * 32);
    GAT_BODY(adB00, adB01, adB10, adB11, w2B0, w2B1, bB0, bB1, bB2, bB3,
             w2A0, w2A1, bA0, bA1, bA2, bA3, jbeg + b2 * 32, b2, jbeg + b3 * 32);
  }

  // row-sums: combine the 4 k-quads; every lane ends with full sum for its m
  rsum0 += __shfl_xor(rsum0, 16);
  rsum0 += __shfl_xor(rsum0, 32);
  rsum1 += __shfl_xor(rsum1, 16);
  rsum1 += __shfl_xor(rsum1, 32);

  const int slice = (nslices > 1) ? jc : 0;
  float* accout = accbuf + (size_t)slice * (NN * FOUT);
  float* denout = denbuf + slice * NN;
  f32x4 cc0[4] = {c00, c01, c02, c03};
  f32x4 cc1[4] = {c10, c11, c12, c13};
  if (nslices > 1) {            // roomy ws: plain per-slice stores
    if (q == 0) { denout[r0] = rsum0; denout[r1] = rsum1; }
#pragma unroll
    for (int ft = 0; ft < 4; ++ft)
#pragma unroll
      for (int r = 0; r < 4; ++r) {
        accout[(rg * 32 +      q * 4 + r) * FOUT + ft * 16 + m] = cc0[ft][r];
        accout[(rg * 32 + 16 + q * 4 + r) * FOUT + ft * 16 + m] = cc1[ft][r];
      }
  } else {                      // tight ws: atomic accumulate (zeroed first)
    if (q == 0) { atomicAdd(&denout[r0], rsum0); atomicAdd(&denout[r1], rsum1); }
#pragma unroll
    for (int ft = 0; ft < 4; ++ft)
#pragma unroll
      for (int r = 0; r < 4; ++r) {
        atomicAdd(&accout[(rg * 32 +      q * 4 + r) * FOUT + ft * 16 + m], cc0[ft][r]);
        atomicAdd(&accout[(rg * 32 + 16 + q * 4 + r) * FOUT + ft * 16 + m], cc1[ft][r]);
      }
  }
}

// ---------------------------------------------------------------- Phase C ---
// elu(acc/den), vectorized f32x4 per thread.
__global__ __launch_bounds__(256) void gat_phaseC(
    const float* __restrict__ accbuf, const float* __restrict__ denbuf,
    float* __restrict__ out, int nslices)
{
  const int idx4 = blockIdx.x * 256 + threadIdx.x;   // f32x4 index
  const int idx  = idx4 * 4;
  const int row  = idx >> 6;    // FOUT = 64; 4 elems stay within one row
  f32x4 s = {0.f, 0.f, 0.f, 0.f};
  float d = 0.f;
  for (int sl = 0; sl < nslices; ++sl) {
    f32x4 v = *(const f32x4*)(accbuf + (size_t)sl * (NN * FOUT) + idx);
    s += v;
    d += denbuf[sl * NN + row];
  }
  float inv = 1.0f / d;
  f32x4 o;
#pragma unroll
  for (int e = 0; e < 4; ++e) {
    float v = s[e] * inv;
    o[e] = (v > 0.f) ? v : expm1f(v);   // elu, alpha=1
  }
  *(f32x4*)(out + idx) = o;
}

// ------------------------------------------------------------------ launch --
extern "C" void kernel_launch(void* const* d_in, const int* in_sizes, int n_in,
                              void* d_out, int out_size, void* d_ws, size_t ws_size,
                              hipStream_t stream)
{
  const float* x   = (const float*)d_in[0];   // [8192,128]
  const float* adj = (const float*)d_in[1];   // [8192,8192]
  const float* W   = (const float*)d_in[2];   // [128,64]
  const float* a   = (const float*)d_in[3];   // [128,1]
  float* out = (float*)d_out;                 // [8192,64] fp32

  const size_t accEl = (size_t)NN * FOUT;
  const size_t whpBytes = (size_t)(NN / 32) * 4 * 512 * 2;   // 1 MB packed B
  const size_t roomyBytes = (size_t)SJ * accEl * 4 + (size_t)SJ * NN * 4
                          + (size_t)NN * 8 + whpBytes;
  const int nslices = (ws_size >= roomyBytes) ? SJ : 1;

  char* ws = (char*)d_ws;
  float* accbuf = (float*)ws;
  size_t off = (size_t)nslices * accEl * 4;
  float* denbuf = (float*)(ws + off); off += (size_t)nslices * NN * 4;
  float* Wh1 = (float*)(ws + off);    off += (size_t)NN * 4;
  float* Wh2 = (float*)(ws + off);    off += (size_t)NN * 4;
  unsigned short* WhP = (unsigned short*)(ws + off);

  if (nslices == 1)   // atomic path needs zeroed acc+den (contiguous)
    hipMemsetAsync(accbuf, 0, accEl * 4 + (size_t)NN * 4, stream);

  gat_phaseA<<<NN / 16, 256, 0, stream>>>(x, W, a, WhP, Wh1, Wh2);
  gat_phaseB<<<((NN / 32) * SJ) / 4, 256, 0, stream>>>(adj, WhP, Wh1, Wh2,
                                                       accbuf, denbuf, nslices);
  gat_phaseC<<<(NN * FOUT) / 4 / 256, 256, 0, stream>>>(accbuf, denbuf, out, nslices);
}

// Round 9
// 378.300 us; speedup vs baseline: 1.1285x; 1.0428x over previous
//
#include <hip/hip_runtime.h>
#include <cstdint>
#include <cstddef>

// GAT layer, N=8192, Fin=128, Fout=64.
// h = elu( softmax_j(mask(leaky_relu(Wh1_i + Wh2_j))) @ Wh )
// R13 = R12 with the B operand moved to LDS. The WG's 4 waves share one
// j-chunk whose packed-B panel is exactly 64 KB (WhP[jc], contiguous) ->
// cooperative copy to static LDS once, then body B-frags are ds_read_b128
// (lgkmcnt) -- OFF the in-order vmcnt queue. Remaining vmcnt users: the
// distance-2 NT adj stream + distance-1 w2 pair (2 loads). Rationale:
// R11 proved a ~92us adj-independent body floor; R8+Little's-law gives
// ~13k cy stall/body -- global-miss latency on B under adj-stream cache
// churn, unhideable at 3 waves/SIMD. LDS B removes those wait-points.
// 64KB LDS -> 2 WG/CU -> 1024 WGs = 2 clean rounds.

#define NN   8192
#define FIN  128
#define FOUT 64
#define SJ   16                // j-split per 32-row group: 256*SJ = 4096 tasks
#define JCHUNK (NN / SJ)       // 512 columns per wave -> 16 blocks of 32

typedef __attribute__((ext_vector_type(8))) short   short8;   // 8 bf16 (4 VGPRs)
typedef __attribute__((ext_vector_type(4))) float   f32x4;

#define LOG2E 1.44269504088896340736f
#define NTL(p) __builtin_nontemporal_load((const f32x4*)(p))

// ---------------------------------------------------------------- Phase A ---
// One wave per 4 rows: Wh[row][f] (f = lane). Emits:
//  - WhP packed B-fragments: WhP[(B0*4+ft)*512 + lane*8 + e] =
//      bf16(Wh[B0*32 + (lane>>4)*8 + e][ (ft*16) + (lane&15) ])
//    i.e. exactly the 16B lane (m,q) consumes as MFMA-B in phaseB.
//  - Wh1/Wh2 = Wh.a1 / Wh.a2, pre-scaled by log2e (exp2 domain; leaky_relu
//    commutes with positive scaling).
__global__ __launch_bounds__(256) void gat_phaseA(
    const float* __restrict__ x, const float* __restrict__ W,
    const float* __restrict__ a, unsigned short* __restrict__ WhP,
    float* __restrict__ Wh1, float* __restrict__ Wh2)
{
  const int wid  = threadIdx.x >> 6;
  const int lane = threadIdx.x & 63;
  const int row0 = (blockIdx.x * 4 + wid) * 4;
  const float a1 = a[lane];
  const float a2 = a[FOUT + lane];
  float acc[4] = {0.f, 0.f, 0.f, 0.f};
#pragma unroll 4
  for (int k = 0; k < FIN; k += 4) {
    float4 wv0 = make_float4(W[(k+0)*FOUT + lane], W[(k+1)*FOUT + lane],
                             W[(k+2)*FOUT + lane], W[(k+3)*FOUT + lane]);
#pragma unroll
    for (int r = 0; r < 4; ++r) {
      float4 xv = *(const float4*)(x + (row0 + r) * FIN + k);
      acc[r] = fmaf(xv.x, wv0.x, acc[r]);
      acc[r] = fmaf(xv.y, wv0.y, acc[r]);
      acc[r] = fmaf(xv.z, wv0.z, acc[r]);
      acc[r] = fmaf(xv.w, wv0.w, acc[r]);
    }
  }
  const int ft = lane >> 4, m = lane & 15;
#pragma unroll
  for (int r = 0; r < 4; ++r) {
    const int row = row0 + r;
    // bf16 round-to-nearest-even
    unsigned int u = __float_as_uint(acc[r]);
    unsigned int rb = (u + 0x7FFFu + ((u >> 16) & 1u)) >> 16;
    // packed-fragment dest: B0=row>>5, q=(row>>3)&3, e=row&7
    const int B0 = row >> 5, qq = (row >> 3) & 3, e = row & 7;
    WhP[(size_t)(B0 * 4 + ft) * 512 + (qq * 16 + m) * 8 + e] = (unsigned short)rb;
    float s1 = acc[r] * a1, s2 = acc[r] * a2;
#pragma unroll
    for (int off = 32; off; off >>= 1) {
      s1 += __shfl_xor(s1, off);
      s2 += __shfl_xor(s2, off);
    }
    if (lane == 0) { Wh1[row] = s1 * LOG2E; Wh2[row] = s2 * LOG2E; }
  }
}

// ---------------------------------------------------------------- Phase B ---
// Wave task = (rowGroup of 32 rows) x (j-chunk of 512). 4 waves/WG share the
// j-chunk; its full packed-B panel (64 KB) is staged in LDS once. Per body:
// 4 ds_read_b128 B-frags (lgkmcnt, hidden under af compute) + distance-1 w2
// pair + distance-2 NT adj stream (the only vmcnt users). 16 blocks of 32
// cols, unrolled x2 ping-pong on adj/w2 regs.
#define AF_ONE(AF, AD0, AD1, W20, W21, WH1, RS)                          \
    _Pragma("unroll")                                                    \
    for (int e = 0; e < 4; ++e) {                                        \
      float t0 = (WH1) + (W20)[e];                                       \
      t0 = fmaxf(t0, 0.2f * t0);            /* leaky_relu, scale-inv */  \
      float p0 = exp2f(t0) * (AD0)[e];      /* mask: adj is 0.0/1.0 */   \
      unsigned int pu0 = __float_as_uint(p0) & 0xFFFF0000u;              \
      RS += __uint_as_float(pu0);           /* denom matches bf16 num */ \
      AF[e] = (short)(pu0 >> 16);                                        \
      float t1 = (WH1) + (W21)[e];                                       \
      t1 = fmaxf(t1, 0.2f * t1);                                         \
      float p1 = exp2f(t1) * (AD1)[e];                                   \
      unsigned int pu1 = __float_as_uint(p1) & 0xFFFF0000u;              \
      RS += __uint_as_float(pu1);                                        \
      AF[4 + e] = (short)(pu1 >> 16);                                    \
    }

#define GAT_BODY(AD00, AD01, AD10, AD11, W2C0, W2C1, W2N0, W2N1,         \
                 BLK, JN1, JN2)                                          \
  {                                                                      \
    const unsigned short* pb = panel + (BLK) * 2048 + lane * 8;          \
    short8 b0 = *(const short8*)(pb);                                    \
    short8 b1 = *(const short8*)(pb + 512);                              \
    short8 b2 = *(const short8*)(pb + 1024);                             \
    short8 b3 = *(const short8*)(pb + 1536);                             \
    W2N0 = *(const f32x4*)(w2base + (JN1));                              \
    W2N1 = *(const f32x4*)(w2base + (JN1) + 4);                          \
    short8 af0, af1;                                                     \
    AF_ONE(af0, AD00, AD01, W2C0, W2C1, wh1_0, rsum0);                   \
    AF_ONE(af1, AD10, AD11, W2C0, W2C1, wh1_1, rsum1);                   \
    AD00 = NTL(adjrow0 + (JN2)); AD01 = NTL(adjrow0 + (JN2) + 4);        \
    AD10 = NTL(adjrow1 + (JN2)); AD11 = NTL(adjrow1 + (JN2) + 4);        \
    c00 = __builtin_amdgcn_mfma_f32_16x16x32_bf16(af0, b0, c00, 0,0,0);  \
    c01 = __builtin_amdgcn_mfma_f32_16x16x32_bf16(af0, b1, c01, 0,0,0);  \
    c02 = __builtin_amdgcn_mfma_f32_16x16x32_bf16(af0, b2, c02, 0,0,0);  \
    c03 = __builtin_amdgcn_mfma_f32_16x16x32_bf16(af0, b3, c03, 0,0,0);  \
    c10 = __builtin_amdgcn_mfma_f32_16x16x32_bf16(af1, b0, c10, 0,0,0);  \
    c11 = __builtin_amdgcn_mfma_f32_16x16x32_bf16(af1, b1, c11, 0,0,0);  \
    c12 = __builtin_amdgcn_mfma_f32_16x16x32_bf16(af1, b2, c12, 0,0,0);  \
    c13 = __builtin_amdgcn_mfma_f32_16x16x32_bf16(af1, b3, c13, 0,0,0);  \
  }

__global__ __launch_bounds__(256, 2) void gat_phaseB(
    const float* __restrict__ adj, const unsigned short* __restrict__ WhP,
    const float* __restrict__ Wh1, const float* __restrict__ Wh2,
    float* __restrict__ accbuf, float* __restrict__ denbuf, int nslices)
{
  const int wid  = threadIdx.x >> 6;
  const int lane = threadIdx.x & 63;
  // 4 waves of a WG share the j-chunk, cover 4 row-groups
  const int jc   = blockIdx.x % SJ;
  const int rg   = (blockIdx.x / SJ) * 4 + wid;   // 32-row group
  const int m = lane & 15;
  const int q = lane >> 4;
  const int r0 = rg * 32 + m;
  const int r1 = r0 + 16;
  const float wh1_0 = Wh1[r0];
  const float wh1_1 = Wh1[r1];
  // per-lane bases with the q*8 element offset folded in
  const float* adjrow0 = adj + (size_t)r0 * NN + q * 8;
  const float* adjrow1 = adj + (size_t)r1 * NN + q * 8;
  const float* w2base = Wh2 + q * 8;

  // ---- 64 KB LDS panel: this jc's full packed-B (16 blocks x 2048 shorts)
  __shared__ __align__(16) unsigned short panel[16 * 2048];
  {
    const f32x4* src = (const f32x4*)(WhP + (size_t)jc * 16 * 2048) + threadIdx.x;
    f32x4* dst = (f32x4*)panel + threadIdx.x;
#pragma unroll
    for (int k = 0; k < 16; ++k)
      dst[k * 256] = src[k * 256];     // 256 thr x 16B = 4 KB per step
  }
  __syncthreads();

  f32x4 c00 = {0.f,0.f,0.f,0.f}, c01 = c00, c02 = c00, c03 = c00;
  f32x4 c10 = c00, c11 = c00, c12 = c00, c13 = c00;
  float rsum0 = 0.f, rsum1 = 0.f;

  const int jbeg = jc * JCHUNK;

  // ping-pong slots: A = even blocks, B = odd blocks (adj + w2 only)
  f32x4 w2A0, w2A1, w2B0, w2B1;
  f32x4 adA00, adA01, adA10, adA11;    // sub-tile 0/1, block-even
  f32x4 adB00, adB01, adB10, adB11;    // block-odd

  // prologue: w2 for block 0, adj for blocks 0 and 1
  w2A0 = *(const f32x4*)(w2base + jbeg);
  w2A1 = *(const f32x4*)(w2base + jbeg + 4);
  adA00 = NTL(adjrow0 + jbeg);      adA01 = NTL(adjrow0 + jbeg + 4);
  adA10 = NTL(adjrow1 + jbeg);      adA11 = NTL(adjrow1 + jbeg + 4);
  adB00 = NTL(adjrow0 + jbeg + 32); adB01 = NTL(adjrow0 + jbeg + 36);
  adB10 = NTL(adjrow1 + jbeg + 32); adB11 = NTL(adjrow1 + jbeg + 36);

  // 16 blocks of 32 columns; unrolled x2 -> 8 static double-bodies. Tail
  // "next" loads wrap (valid addresses, values unused).
#pragma unroll
  for (int bb = 0; bb < 16; bb += 2) {
    const int j1 = ((bb + 1) & 15) * 32;
    const int j2 = ((bb + 2) & 15) * 32;
    const int j3 = ((bb + 3) & 15) * 32;
    GAT_BODY(adA00, adA01, adA10, adA11, w2A0, w2A1, w2B0, w2B1,
             bb,     jbeg + j1, jbeg + j2);
    GAT_BODY(adB00, adB01, adB10, adB11, w2B0, w2B1, w2A0, w2A1,
             bb + 1, jbeg + j2, jbeg + j3);
  }

  // row-sums: combine the 4 k-quads; every lane ends with full sum for its m
  rsum0 += __shfl_xor(rsum0, 16);
  rsum0 += __shfl_xor(rsum0, 32);
  rsum1 += __shfl_xor(rsum1, 16);
  rsum1 += __shfl_xor(rsum1, 32);

  const int slice = (nslices > 1) ? jc : 0;
  float* accout = accbuf + (size_t)slice * (NN * FOUT);
  float* denout = denbuf + slice * NN;
  f32x4 cc0[4] = {c00, c01, c02, c03};
  f32x4 cc1[4] = {c10, c11, c12, c13};
  if (nslices > 1) {            // roomy ws: plain per-slice stores
    if (q == 0) { denout[r0] = rsum0; denout[r1] = rsum1; }
#pragma unroll
    for (int ft = 0; ft < 4; ++ft)
#pragma unroll
      for (int r = 0; r < 4; ++r) {
        accout[(rg * 32 +      q * 4 + r) * FOUT + ft * 16 + m] = cc0[ft][r];
        accout[(rg * 32 + 16 + q * 4 + r) * FOUT + ft * 16 + m] = cc1[ft][r];
      }
  } else {                      // tight ws: atomic accumulate (zeroed first)
    if (q == 0) { atomicAdd(&denout[r0], rsum0); atomicAdd(&denout[r1], rsum1); }
#pragma unroll
    for (int ft = 0; ft < 4; ++ft)
#pragma unroll
      for (int r = 0; r < 4; ++r) {
        atomicAdd(&accout[(rg * 32 +      q * 4 + r) * FOUT + ft * 16 + m], cc0[ft][r]);
        atomicAdd(&accout[(rg * 32 + 16 + q * 4 + r) * FOUT + ft * 16 + m], cc1[ft][r]);
      }
  }
}

// ---------------------------------------------------------------- Phase C ---
// elu(acc/den), vectorized f32x4 per thread.
__global__ __launch_bounds__(256) void gat_phaseC(
    const float* __restrict__ accbuf, const float* __restrict__ denbuf,
    float* __restrict__ out, int nslices)
{
  const int idx4 = blockIdx.x * 256 + threadIdx.x;   // f32x4 index
  const int idx  = idx4 * 4;
  const int row  = idx >> 6;    // FOUT = 64; 4 elems stay within one row
  f32x4 s = {0.f, 0.f, 0.f, 0.f};
  float d = 0.f;
  for (int sl = 0; sl < nslices; ++sl) {
    f32x4 v = *(const f32x4*)(accbuf + (size_t)sl * (NN * FOUT) + idx);
    s += v;
    d += denbuf[sl * NN + row];
  }
  float inv = 1.0f / d;
  f32x4 o;
#pragma unroll
  for (int e = 0; e < 4; ++e) {
    float v = s[e] * inv;
    o[e] = (v > 0.f) ? v : expm1f(v);   // elu, alpha=1
  }
  *(f32x4*)(out + idx) = o;
}

// ------------------------------------------------------------------ launch --
extern "C" void kernel_launch(void* const* d_in, const int* in_sizes, int n_in,
                              void* d_out, int out_size, void* d_ws, size_t ws_size,
                              hipStream_t stream)
{
  const float* x   = (const float*)d_in[0];   // [8192,128]
  const float* adj = (const float*)d_in[1];   // [8192,8192]
  const float* W   = (const float*)d_in[2];   // [128,64]
  const float* a   = (const float*)d_in[3];   // [128,1]
  float* out = (float*)d_out;                 // [8192,64] fp32

  const size_t accEl = (size_t)NN * FOUT;
  const size_t whpBytes = (size_t)(NN / 32) * 4 * 512 * 2;   // 1 MB packed B
  const size_t roomyBytes = (size_t)SJ * accEl * 4 + (size_t)SJ * NN * 4
                          + (size_t)NN * 8 + whpBytes;
  const int nslices = (ws_size >= roomyBytes) ? SJ : 1;

  char* ws = (char*)d_ws;
  float* accbuf = (float*)ws;
  size_t off = (size_t)nslices * accEl * 4;
  float* denbuf = (float*)(ws + off); off += (size_t)nslices * NN * 4;
  float* Wh1 = (float*)(ws + off);    off += (size_t)NN * 4;
  float* Wh2 = (float*)(ws + off);    off += (size_t)NN * 4;
  unsigned short* WhP = (unsigned short*)(ws + off);

  if (nslices == 1)   // atomic path needs zeroed acc+den (contiguous)
    hipMemsetAsync(accbuf, 0, accEl * 4 + (size_t)NN * 4, stream);

  gat_phaseA<<<NN / 16, 256, 0, stream>>>(x, W, a, WhP, Wh1, Wh2);
  gat_phaseB<<<((NN / 32) * SJ) / 4, 256, 0, stream>>>(adj, WhP, Wh1, Wh2,
                                                       accbuf, denbuf, nslices);
  gat_phaseC<<<(NN * FOUT) / 4 / 256, 256, 0, stream>>>(accbuf, denbuf, out, nslices);
}

// Round 10
// 377.225 us; speedup vs baseline: 1.1317x; 1.0028x over previous
//
#include <hip/hip_runtime.h>
#include <cstdint>
#include <cstddef>

// GAT layer, N=8192, Fin=128, Fout=64.
// h = elu( softmax_j(mask(leaky_relu(Wh1_i + Wh2_j))) @ Wh )
// R14 = R13 (378us: packed-B panel in LDS, off the vmcnt queue) + two moves:
//  1. Wh2 j-chunk (2 KB) also staged to LDS -> body has ZERO per-body L2
//     wait-points; the vmcnt queue carries only the adj stream.
//  2. adj prefetch deepened distance-2 -> distance-4 (4 reg slots, 64 VGPR,
//     affordable at 2 waves/SIMD): ~1600cy slack vs ~900cy HBM latency.
// Stall model (3 rounds confirmed): phaseB = per-body vmcnt wait-points x
// miss latency; each removed wait-point class has paid (R9 -34us, R13 -16us).

#define NN   8192
#define FIN  128
#define FOUT 64
#define SJ   16                // j-split per 32-row group: 256*SJ = 4096 tasks
#define JCHUNK (NN / SJ)       // 512 columns per wave -> 16 blocks of 32

typedef __attribute__((ext_vector_type(8))) short   short8;   // 8 bf16 (4 VGPRs)
typedef __attribute__((ext_vector_type(4))) float   f32x4;

#define LOG2E 1.44269504088896340736f
#define NTL(p) __builtin_nontemporal_load((const f32x4*)(p))

// ---------------------------------------------------------------- Phase A ---
// One wave per 4 rows: Wh[row][f] (f = lane). Emits:
//  - WhP packed B-fragments: WhP[(B0*4+ft)*512 + lane*8 + e] =
//      bf16(Wh[B0*32 + (lane>>4)*8 + e][ (ft*16) + (lane&15) ])
//    i.e. exactly the 16B lane (m,q) consumes as MFMA-B in phaseB.
//  - Wh1/Wh2 = Wh.a1 / Wh.a2, pre-scaled by log2e (exp2 domain; leaky_relu
//    commutes with positive scaling).
__global__ __launch_bounds__(256) void gat_phaseA(
    const float* __restrict__ x, const float* __restrict__ W,
    const float* __restrict__ a, unsigned short* __restrict__ WhP,
    float* __restrict__ Wh1, float* __restrict__ Wh2)
{
  const int wid  = threadIdx.x >> 6;
  const int lane = threadIdx.x & 63;
  const int row0 = (blockIdx.x * 4 + wid) * 4;
  const float a1 = a[lane];
  const float a2 = a[FOUT + lane];
  float acc[4] = {0.f, 0.f, 0.f, 0.f};
#pragma unroll 4
  for (int k = 0; k < FIN; k += 4) {
    float4 wv0 = make_float4(W[(k+0)*FOUT + lane], W[(k+1)*FOUT + lane],
                             W[(k+2)*FOUT + lane], W[(k+3)*FOUT + lane]);
#pragma unroll
    for (int r = 0; r < 4; ++r) {
      float4 xv = *(const float4*)(x + (row0 + r) * FIN + k);
      acc[r] = fmaf(xv.x, wv0.x, acc[r]);
      acc[r] = fmaf(xv.y, wv0.y, acc[r]);
      acc[r] = fmaf(xv.z, wv0.z, acc[r]);
      acc[r] = fmaf(xv.w, wv0.w, acc[r]);
    }
  }
  const int ft = lane >> 4, m = lane & 15;
#pragma unroll
  for (int r = 0; r < 4; ++r) {
    const int row = row0 + r;
    // bf16 round-to-nearest-even
    unsigned int u = __float_as_uint(acc[r]);
    unsigned int rb = (u + 0x7FFFu + ((u >> 16) & 1u)) >> 16;
    // packed-fragment dest: B0=row>>5, q=(row>>3)&3, e=row&7
    const int B0 = row >> 5, qq = (row >> 3) & 3, e = row & 7;
    WhP[(size_t)(B0 * 4 + ft) * 512 + (qq * 16 + m) * 8 + e] = (unsigned short)rb;
    float s1 = acc[r] * a1, s2 = acc[r] * a2;
#pragma unroll
    for (int off = 32; off; off >>= 1) {
      s1 += __shfl_xor(s1, off);
      s2 += __shfl_xor(s2, off);
    }
    if (lane == 0) { Wh1[row] = s1 * LOG2E; Wh2[row] = s2 * LOG2E; }
  }
}

// ---------------------------------------------------------------- Phase B ---
// Wave task = (rowGroup of 32 rows) x (j-chunk of 512). 4 waves/WG share the
// j-chunk; full packed-B panel (64 KB) + Wh2 chunk (2 KB) staged in LDS once.
// Body: 4 ds_read_b128 B-frags + 2 ds_read w2 (all lgkmcnt, hidden under af
// compute); adj is the ONLY vmcnt user, prefetched distance-4 in 4 reg slots.
// 16 blocks of 32 cols, fully unrolled x4.
#define AF_ONE(AF, AD0, AD1, W20, W21, WH1, RS)                          \
    _Pragma("unroll")                                                    \
    for (int e = 0; e < 4; ++e) {                                        \
      float t0 = (WH1) + (W20)[e];                                       \
      t0 = fmaxf(t0, 0.2f * t0);            /* leaky_relu, scale-inv */  \
      float p0 = exp2f(t0) * (AD0)[e];      /* mask: adj is 0.0/1.0 */   \
      unsigned int pu0 = __float_as_uint(p0) & 0xFFFF0000u;              \
      RS += __uint_as_float(pu0);           /* denom matches bf16 num */ \
      AF[e] = (short)(pu0 >> 16);                                        \
      float t1 = (WH1) + (W21)[e];                                       \
      t1 = fmaxf(t1, 0.2f * t1);                                         \
      float p1 = exp2f(t1) * (AD1)[e];                                   \
      unsigned int pu1 = __float_as_uint(p1) & 0xFFFF0000u;              \
      RS += __uint_as_float(pu1);                                        \
      AF[4 + e] = (short)(pu1 >> 16);                                    \
    }

#define GAT_BODY(AD00, AD01, AD10, AD11, BLK, JPF)                       \
  {                                                                      \
    const unsigned short* pb = panel + (BLK) * 2048 + lane * 8;          \
    short8 b0 = *(const short8*)(pb);                                    \
    short8 b1 = *(const short8*)(pb + 512);                              \
    short8 b2 = *(const short8*)(pb + 1024);                             \
    short8 b3 = *(const short8*)(pb + 1536);                             \
    const float* wp = w2lds + (BLK) * 32 + q * 8;                        \
    f32x4 w20 = *(const f32x4*)(wp);                                     \
    f32x4 w21 = *(const f32x4*)(wp + 4);                                 \
    short8 af0, af1;                                                     \
    AF_ONE(af0, AD00, AD01, w20, w21, wh1_0, rsum0);                     \
    AF_ONE(af1, AD10, AD11, w20, w21, wh1_1, rsum1);                     \
    AD00 = NTL(adjrow0 + (JPF)); AD01 = NTL(adjrow0 + (JPF) + 4);        \
    AD10 = NTL(adjrow1 + (JPF)); AD11 = NTL(adjrow1 + (JPF) + 4);        \
    c00 = __builtin_amdgcn_mfma_f32_16x16x32_bf16(af0, b0, c00, 0,0,0);  \
    c01 = __builtin_amdgcn_mfma_f32_16x16x32_bf16(af0, b1, c01, 0,0,0);  \
    c02 = __builtin_amdgcn_mfma_f32_16x16x32_bf16(af0, b2, c02, 0,0,0);  \
    c03 = __builtin_amdgcn_mfma_f32_16x16x32_bf16(af0, b3, c03, 0,0,0);  \
    c10 = __builtin_amdgcn_mfma_f32_16x16x32_bf16(af1, b0, c10, 0,0,0);  \
    c11 = __builtin_amdgcn_mfma_f32_16x16x32_bf16(af1, b1, c11, 0,0,0);  \
    c12 = __builtin_amdgcn_mfma_f32_16x16x32_bf16(af1, b2, c12, 0,0,0);  \
    c13 = __builtin_amdgcn_mfma_f32_16x16x32_bf16(af1, b3, c13, 0,0,0);  \
  }

__global__ __launch_bounds__(256, 2) void gat_phaseB(
    const float* __restrict__ adj, const unsigned short* __restrict__ WhP,
    const float* __restrict__ Wh1, const float* __restrict__ Wh2,
    float* __restrict__ accbuf, float* __restrict__ denbuf, int nslices)
{
  const int wid  = threadIdx.x >> 6;
  const int lane = threadIdx.x & 63;
  // 4 waves of a WG share the j-chunk, cover 4 row-groups
  const int jc   = blockIdx.x % SJ;
  const int rg   = (blockIdx.x / SJ) * 4 + wid;   // 32-row group
  const int m = lane & 15;
  const int q = lane >> 4;
  const int r0 = rg * 32 + m;
  const int r1 = r0 + 16;
  const float wh1_0 = Wh1[r0];
  const float wh1_1 = Wh1[r1];
  // per-lane bases with the q*8 element offset folded in
  const float* adjrow0 = adj + (size_t)r0 * NN + q * 8;
  const float* adjrow1 = adj + (size_t)r1 * NN + q * 8;

  const int jbeg = jc * JCHUNK;

  // ---- adj prologue: distance-4 slots (issued first, deepest in queue)
  f32x4 aS00, aS01, aS10, aS11;   // slot A: block 0
  f32x4 bS00, bS01, bS10, bS11;   // slot B: block 1
  f32x4 cS00, cS01, cS10, cS11;   // slot C: block 2
  f32x4 dS00, dS01, dS10, dS11;   // slot D: block 3
  aS00 = NTL(adjrow0 + jbeg);       aS01 = NTL(adjrow0 + jbeg + 4);
  aS10 = NTL(adjrow1 + jbeg);       aS11 = NTL(adjrow1 + jbeg + 4);
  bS00 = NTL(adjrow0 + jbeg + 32);  bS01 = NTL(adjrow0 + jbeg + 36);
  bS10 = NTL(adjrow1 + jbeg + 32);  bS11 = NTL(adjrow1 + jbeg + 36);
  cS00 = NTL(adjrow0 + jbeg + 64);  cS01 = NTL(adjrow0 + jbeg + 68);
  cS10 = NTL(adjrow1 + jbeg + 64);  cS11 = NTL(adjrow1 + jbeg + 68);
  dS00 = NTL(adjrow0 + jbeg + 96);  dS01 = NTL(adjrow0 + jbeg + 100);
  dS10 = NTL(adjrow1 + jbeg + 96);  dS11 = NTL(adjrow1 + jbeg + 100);

  // ---- LDS: 64 KB packed-B panel + 2 KB Wh2 chunk for this jc
  __shared__ __align__(16) unsigned short panel[16 * 2048];
  __shared__ __align__(16) float w2lds[JCHUNK];
  {
    const f32x4* src = (const f32x4*)(WhP + (size_t)jc * 16 * 2048) + threadIdx.x;
    f32x4* dst = (f32x4*)panel + threadIdx.x;
#pragma unroll
    for (int k = 0; k < 16; ++k)
      dst[k * 256] = src[k * 256];     // 256 thr x 16B = 4 KB per step
    if (threadIdx.x < JCHUNK / 4)
      ((f32x4*)w2lds)[threadIdx.x] =
          ((const f32x4*)(Wh2 + jbeg))[threadIdx.x];
  }
  __syncthreads();

  f32x4 c00 = {0.f,0.f,0.f,0.f}, c01 = c00, c02 = c00, c03 = c00;
  f32x4 c10 = c00, c11 = c00, c12 = c00, c13 = c00;
  float rsum0 = 0.f, rsum1 = 0.f;

  // 16 blocks of 32 columns; 4-slot rotation, distance-4 prefetch. Tail
  // prefetches wrap (valid addresses, values unused).
#pragma unroll
  for (int bb = 0; bb < 16; bb += 4) {
    GAT_BODY(aS00, aS01, aS10, aS11, bb,     jbeg + ((bb + 4) & 15) * 32);
    GAT_BODY(bS00, bS01, bS10, bS11, bb + 1, jbeg + ((bb + 5) & 15) * 32);
    GAT_BODY(cS00, cS01, cS10, cS11, bb + 2, jbeg + ((bb + 6) & 15) * 32);
    GAT_BODY(dS00, dS01, dS10, dS11, bb + 3, jbeg + ((bb + 7) & 15) * 32);
  }

  // row-sums: combine the 4 k-quads; every lane ends with full sum for its m
  rsum0 += __shfl_xor(rsum0, 16);
  rsum0 += __shfl_xor(rsum0, 32);
  rsum1 += __shfl_xor(rsum1, 16);
  rsum1 += __shfl_xor(rsum1, 32);

  const int slice = (nslices > 1) ? jc : 0;
  float* accout = accbuf + (size_t)slice * (NN * FOUT);
  float* denout = denbuf + slice * NN;
  f32x4 cc0[4] = {c00, c01, c02, c03};
  f32x4 cc1[4] = {c10, c11, c12, c13};
  if (nslices > 1) {            // roomy ws: plain per-slice stores
    if (q == 0) { denout[r0] = rsum0; denout[r1] = rsum1; }
#pragma unroll
    for (int ft = 0; ft < 4; ++ft)
#pragma unroll
      for (int r = 0; r < 4; ++r) {
        accout[(rg * 32 +      q * 4 + r) * FOUT + ft * 16 + m] = cc0[ft][r];
        accout[(rg * 32 + 16 + q * 4 + r) * FOUT + ft * 16 + m] = cc1[ft][r];
      }
  } else {                      // tight ws: atomic accumulate (zeroed first)
    if (q == 0) { atomicAdd(&denout[r0], rsum0); atomicAdd(&denout[r1], rsum1); }
#pragma unroll
    for (int ft = 0; ft < 4; ++ft)
#pragma unroll
      for (int r = 0; r < 4; ++r) {
        atomicAdd(&accout[(rg * 32 +      q * 4 + r) * FOUT + ft * 16 + m], cc0[ft][r]);
        atomicAdd(&accout[(rg * 32 + 16 + q * 4 + r) * FOUT + ft * 16 + m], cc1[ft][r]);
      }
  }
}

// ---------------------------------------------------------------- Phase C ---
// elu(acc/den), vectorized f32x4 per thread.
__global__ __launch_bounds__(256) void gat_phaseC(
    const float* __restrict__ accbuf, const float* __restrict__ denbuf,
    float* __restrict__ out, int nslices)
{
  const int idx4 = blockIdx.x * 256 + threadIdx.x;   // f32x4 index
  const int idx  = idx4 * 4;
  const int row  = idx >> 6;    // FOUT = 64; 4 elems stay within one row
  f32x4 s = {0.f, 0.f, 0.f, 0.f};
  float d = 0.f;
  for (int sl = 0; sl < nslices; ++sl) {
    f32x4 v = *(const f32x4*)(accbuf + (size_t)sl * (NN * FOUT) + idx);
    s += v;
    d += denbuf[sl * NN + row];
  }
  float inv = 1.0f / d;
  f32x4 o;
#pragma unroll
  for (int e = 0; e < 4; ++e) {
    float v = s[e] * inv;
    o[e] = (v > 0.f) ? v : expm1f(v);   // elu, alpha=1
  }
  *(f32x4*)(out + idx) = o;
}

// ------------------------------------------------------------------ launch --
extern "C" void kernel_launch(void* const* d_in, const int* in_sizes, int n_in,
                              void* d_out, int out_size, void* d_ws, size_t ws_size,
                              hipStream_t stream)
{
  const float* x   = (const float*)d_in[0];   // [8192,128]
  const float* adj = (const float*)d_in[1];   // [8192,8192]
  const float* W   = (const float*)d_in[2];   // [128,64]
  const float* a   = (const float*)d_in[3];   // [128,1]
  float* out = (float*)d_out;                 // [8192,64] fp32

  const size_t accEl = (size_t)NN * FOUT;
  const size_t whpBytes = (size_t)(NN / 32) * 4 * 512 * 2;   // 1 MB packed B
  const size_t roomyBytes = (size_t)SJ * accEl * 4 + (size_t)SJ * NN * 4
                          + (size_t)NN * 8 + whpBytes;
  const int nslices = (ws_size >= roomyBytes) ? SJ : 1;

  char* ws = (char*)d_ws;
  float* accbuf = (float*)ws;
  size_t off = (size_t)nslices * accEl * 4;
  float* denbuf = (float*)(ws + off); off += (size_t)nslices * NN * 4;
  float* Wh1 = (float*)(ws + off);    off += (size_t)NN * 4;
  float* Wh2 = (float*)(ws + off);    off += (size_t)NN * 4;
  unsigned short* WhP = (unsigned short*)(ws + off);

  if (nslices == 1)   // atomic path needs zeroed acc+den (contiguous)
    hipMemsetAsync(accbuf, 0, accEl * 4 + (size_t)NN * 4, stream);

  gat_phaseA<<<NN / 16, 256, 0, stream>>>(x, W, a, WhP, Wh1, Wh2);
  gat_phaseB<<<((NN / 32) * SJ) / 4, 256, 0, stream>>>(adj, WhP, Wh1, Wh2,
                                                       accbuf, denbuf, nslices);
  gat_phaseC<<<(NN * FOUT) / 4 / 256, 256, 0, stream>>>(accbuf, denbuf, out, nslices);
}